// Round 9
// baseline (911.778 us; speedup 1.0000x reference)
//
#include <hip/hip_runtime.h>

typedef float f4 __attribute__((ext_vector_type(4)));
typedef __attribute__((ext_vector_type(4))) float f32x4;
typedef __attribute__((ext_vector_type(8))) short bf16x8;

#define NV 65536       // total vectors (16*4096)
#define D 64           // embedding dim
#define K 1024         // codebook size
#define BM 128         // vectors per block
#define TILE 128       // codes per LDS tile (8 tiles)
#define MARGIN 4.0e-3f // covers 2*(2^-7*||x||*||e||)*2 + fp32 slop (r8-proven)
#define CAP 16
#define LOSS_OFF 4194304
#define IDX_OFF  4194305

__device__ __forceinline__ unsigned f2bf(float f) {  // RNE fp32->bf16
  unsigned u = __builtin_bit_cast(unsigned, f);
  return (u + 0x7fffu + ((u >> 16) & 1u)) >> 16;
}

// Per-code squared norms, replicating numpy fp32 pairwise-8 summation exactly.
__global__ void vq_prep(const float* __restrict__ E, float* __restrict__ eSq,
                        float* __restrict__ loss) {
  int k = blockIdx.x * 256 + threadIdx.x;
  if (k == 0) *loss = 0.0f;
  if (k < K) {
    const float* row = E + (size_t)k * D;
    float r[8];
#pragma unroll
    for (int j = 0; j < 8; ++j) r[j] = __fmul_rn(row[j], row[j]);
#pragma unroll
    for (int i = 8; i < D; i += 8)
#pragma unroll
      for (int j = 0; j < 8; ++j)
        r[j] = __fadd_rn(r[j], __fmul_rn(row[i + j], row[i + j]));
    eSq[k] = __fadd_rn(
        __fadd_rn(__fadd_rn(r[0], r[1]), __fadd_rn(r[2], r[3])),
        __fadd_rn(__fadd_rn(r[4], r[5]), __fadd_rn(r[6], r[7])));
  }
}

// Stage one 128-code tile of E as bf16 into XOR-swizzled LDS (2 thr/row).
__device__ __forceinline__ void stage_tile(const float* __restrict__ E,
                                           unsigned short* dstbase, int tile,
                                           int t) {
  const int rc = t >> 1, h = t & 1;
  const float* src = E + ((size_t)(tile * TILE + rc)) * D + h * 32;
  char* dst = reinterpret_cast<char*>(dstbase) + rc * 128;
  const int sw = (rc & 7) << 4;
#pragma unroll
  for (int s = 0; s < 4; ++s) {
    f4 a = *reinterpret_cast<const f4*>(src + s * 8);
    f4 b = *reinterpret_cast<const f4*>(src + s * 8 + 4);
    uint4 pk;
    pk.x = f2bf(a[0]) | (f2bf(a[1]) << 16);
    pk.y = f2bf(a[2]) | (f2bf(a[3]) << 16);
    pk.z = f2bf(b[0]) | (f2bf(b[1]) << 16);
    pk.w = f2bf(b[2]) | (f2bf(b[3]) << 16);
    *reinterpret_cast<uint4*>(dst + ((h * 64 + s * 16) ^ sw)) = pk;
  }
}

__device__ __forceinline__ bf16x8 ld_a(const float* p) {
  f4 a = *reinterpret_cast<const f4*>(p);
  f4 b = *reinterpret_cast<const f4*>(p + 4);
  bf16x8 r;
  r[0] = (short)f2bf(a[0]); r[1] = (short)f2bf(a[1]);
  r[2] = (short)f2bf(a[2]); r[3] = (short)f2bf(a[3]);
  r[4] = (short)f2bf(b[0]); r[5] = (short)f2bf(b[1]);
  r[6] = (short)f2bf(b[2]); r[7] = (short)f2bf(b[3]);
  return r;
}

// Single-pass bf16-MFMA filter: phase 0 = seed min on tile 0; phases 1..8 =
// collect candidates (u <= A0 + M) over tiles 1..7,0 with double-buffered
// staging; exact fp32 rescore of candidates (reference-exact chain).
__global__ __launch_bounds__(256, 2) void vq_main(
    const float* __restrict__ X, const float* __restrict__ E,
    const float* __restrict__ eSq, float* __restrict__ out) {
  __shared__ unsigned short EbfL[2][TILE * 64];  // 2 x 16 KB, swizzled
  __shared__ float eSqL[K];                      // 4 KB
  __shared__ unsigned cntL[BM];
  __shared__ unsigned short candL[BM * CAP];     // 4 KB
  __shared__ int sidxL[BM];

  const int t = threadIdx.x;
  const int lane = t & 63;
  const int w = t >> 6;
  const int l15 = lane & 15, l4 = lane >> 4;
  const int bv0 = blockIdx.x * BM;

  // A-fragments straight from global X (L2-hot), converted in registers.
  // mfma_f32_16x16x32_bf16 A-layout: row = l&15, k = (l>>4)*8 + j.
  const float* xv0 = X + (size_t)(bv0 + w * 32 + l15) * D;
  const float* xv1 = xv0 + 16 * D;
  bf16x8 a00 = ld_a(xv0 + l4 * 8);
  bf16x8 a01 = ld_a(xv0 + 32 + l4 * 8);
  bf16x8 a10 = ld_a(xv1 + l4 * 8);
  bf16x8 a11 = ld_a(xv1 + 32 + l4 * 8);

#pragma unroll
  for (int i = 0; i < 4; ++i) eSqL[t + 256 * i] = eSq[t + 256 * i];
  if (t < BM) cntL[t] = 0;
  stage_tile(E, EbfL[0], 0, t);
  __syncthreads();

  float thr[8];

  // ---- phase 0: tile 0 in min-mode; stage tile 1 under it ----
  {
    stage_tile(E, EbfL[1], 1, t);
    float umin[8];
#pragma unroll
    for (int i = 0; i < 8; ++i) umin[i] = 3.4e38f;
    const char* eB = reinterpret_cast<const char*>(EbfL[0]);
#pragma unroll
    for (int ct = 0; ct < 8; ++ct) {
      const int lr = ct * 16 + l15;
      const int rsw = (lr & 7) << 4;
      bf16x8 b0 = *reinterpret_cast<const bf16x8*>(eB + lr * 128 + ((l4 * 16) ^ rsw));
      bf16x8 b1 = *reinterpret_cast<const bf16x8*>(eB + lr * 128 + ((64 + l4 * 16) ^ rsw));
      f32x4 acc0 = {0.f, 0.f, 0.f, 0.f}, acc1 = {0.f, 0.f, 0.f, 0.f};
      acc0 = __builtin_amdgcn_mfma_f32_16x16x32_bf16(a00, b0, acc0, 0, 0, 0);
      acc0 = __builtin_amdgcn_mfma_f32_16x16x32_bf16(a01, b1, acc0, 0, 0, 0);
      acc1 = __builtin_amdgcn_mfma_f32_16x16x32_bf16(a10, b0, acc1, 0, 0, 0);
      acc1 = __builtin_amdgcn_mfma_f32_16x16x32_bf16(a11, b1, acc1, 0, 0, 0);
      const float ee = eSqL[lr];
#pragma unroll
      for (int r = 0; r < 4; ++r) {
        umin[r]     = fminf(umin[r],     __fmaf_rn(-2.0f, acc0[r], ee));
        umin[4 + r] = fminf(umin[4 + r], __fmaf_rn(-2.0f, acc1[r], ee));
      }
    }
    // cross-lane (16-group) min -> per-vector seed threshold A0 + M
#pragma unroll
    for (int i = 0; i < 8; ++i) {
#pragma unroll
      for (int off = 1; off < 16; off <<= 1)
        umin[i] = fminf(umin[i], __shfl_xor(umin[i], off, 64));
      thr[i] = umin[i] + MARGIN;
    }
    __syncthreads();
  }

  // ---- phases 1..8: collect over tiles 1,2,...,7,0 (dbuf staging) ----
#pragma unroll 1
  for (int p = 1; p <= 8; ++p) {
    const int tb = (p == 8) ? 0 : p;
    if (p < 8) stage_tile(E, EbfL[(p + 1) & 1], (p == 7) ? 0 : p + 1, t);
    const char* eB = reinterpret_cast<const char*>(EbfL[p & 1]);
#pragma unroll
    for (int ct = 0; ct < 8; ++ct) {
      const int lr = ct * 16 + l15;
      const int rsw = (lr & 7) << 4;
      bf16x8 b0 = *reinterpret_cast<const bf16x8*>(eB + lr * 128 + ((l4 * 16) ^ rsw));
      bf16x8 b1 = *reinterpret_cast<const bf16x8*>(eB + lr * 128 + ((64 + l4 * 16) ^ rsw));
      f32x4 acc0 = {0.f, 0.f, 0.f, 0.f}, acc1 = {0.f, 0.f, 0.f, 0.f};
      acc0 = __builtin_amdgcn_mfma_f32_16x16x32_bf16(a00, b0, acc0, 0, 0, 0);
      acc0 = __builtin_amdgcn_mfma_f32_16x16x32_bf16(a01, b1, acc0, 0, 0, 0);
      acc1 = __builtin_amdgcn_mfma_f32_16x16x32_bf16(a10, b0, acc1, 0, 0, 0);
      acc1 = __builtin_amdgcn_mfma_f32_16x16x32_bf16(a11, b1, acc1, 0, 0, 0);
      const int gc = tb * TILE + lr;
      const float ee = eSqL[gc];
#pragma unroll
      for (int r = 0; r < 4; ++r) {
        const float u0 = __fmaf_rn(-2.0f, acc0[r], ee);
        if (u0 <= thr[r]) {
          const int v = w * 32 + l4 * 4 + r;
          const unsigned pos = atomicAdd(&cntL[v], 1u);
          if (pos < CAP) candL[v * CAP + pos] = (unsigned short)gc;
        }
        const float u1 = __fmaf_rn(-2.0f, acc1[r], ee);
        if (u1 <= thr[4 + r]) {
          const int v = w * 32 + 16 + l4 * 4 + r;
          const unsigned pos = atomicAdd(&cntL[v], 1u);
          if (pos < CAP) candL[v * CAP + pos] = (unsigned short)gc;
        }
      }
    }
    __syncthreads();
  }

  // ====== exact fp32 rescore (bit-identical chain to passing rounds) ======
  {
    const int v = t >> 1, par = t & 1;
    const int gv = bv0 + v;
    const float* xr = X + (size_t)gv * D;
    float rr[8];
#pragma unroll
    for (int j = 0; j < 8; ++j) rr[j] = __fmul_rn(xr[j], xr[j]);
#pragma unroll
    for (int i = 8; i < 64; i += 8)
#pragma unroll
      for (int j = 0; j < 8; ++j)
        rr[j] = __fadd_rn(rr[j], __fmul_rn(xr[i + j], xr[i + j]));
    const float xx = __fadd_rn(
        __fadd_rn(__fadd_rn(rr[0], rr[1]), __fadd_rn(rr[2], rr[3])),
        __fadd_rn(__fadd_rn(rr[4], rr[5]), __fadd_rn(rr[6], rr[7])));

    float best = 3.4e38f;
    int bi = 0x7fffffff;
    const unsigned n = cntL[v];
    if (n <= CAP) {
      for (unsigned i = par; i < n; i += 2) {
        const int c = candL[v * CAP + i];
        const float* er = E + (size_t)c * D;
        float m = 0.f;
#pragma unroll
        for (int j = 0; j < 64; ++j) m = fmaf(er[j], xr[j], m);
        const float dd = __fsub_rn(__fadd_rn(xx, eSqL[c]), 2.0f * m);
        if (dd < best || (dd == best && c < bi)) { best = dd; bi = c; }
      }
    } else {  // overflow fallback: exact full scan (deterministic, correct)
      for (int c = par; c < K; c += 2) {
        const float* er = E + (size_t)c * D;
        float m = 0.f;
#pragma unroll
        for (int j = 0; j < 64; ++j) m = fmaf(er[j], xr[j], m);
        const float dd = __fsub_rn(__fadd_rn(xx, eSqL[c]), 2.0f * m);
        if (dd < best || (dd == best && c < bi)) { best = dd; bi = c; }
      }
    }
    const float ov = __shfl_xor(best, 1, 64);
    const int oi = __shfl_xor(bi, 1, 64);
    if (ov < best || (ov == best && oi < bi)) { best = ov; bi = oi; }
    if (par == 0) sidxL[v] = bi;
  }
  __syncthreads();

  // ============== epilogue: quantized out, indices, loss ==================
  {
    const int v = t >> 1, h = t & 1;
    const int gv = bv0 + v;
    const int code = sidxL[v];
    const f4* er = reinterpret_cast<const f4*>(E + (size_t)code * D + h * 32);
    const f4* xr = reinterpret_cast<const f4*>(X + (size_t)gv * D + h * 32);
    f4* op = reinterpret_cast<f4*>(out + (size_t)gv * D + h * 32);
    float lsum = 0.f;
#pragma unroll
    for (int i = 0; i < 8; ++i) {
      f4 e4 = er[i], x4 = xr[i];
      float d0 = e4[0] - x4[0], d1 = e4[1] - x4[1];
      float d2 = e4[2] - x4[2], d3 = e4[3] - x4[3];
      lsum += d0 * d0 + d1 * d1 + d2 * d2 + d3 * d3;
      op[i] = e4;
    }
    if (t < BM) out[IDX_OFF + bv0 + t] = (float)sidxL[t];
#pragma unroll
    for (int off = 1; off < 64; off <<= 1) lsum += __shfl_xor(lsum, off, 64);
    if (lane == 0)
      atomicAdd(out + LOSS_OFF, lsum * (1.25f / (float)(NV * (size_t)D)));
  }
}

extern "C" void kernel_launch(void* const* d_in, const int* in_sizes, int n_in,
                              void* d_out, int out_size, void* d_ws, size_t ws_size,
                              hipStream_t stream) {
  const float* X = (const float*)d_in[0];
  const float* E = (const float*)d_in[1];
  float* out = (float*)d_out;
  float* eSq = (float*)d_ws;  // 4 KB scratch
  vq_prep<<<4, 256, 0, stream>>>(E, eSq, out + LOSS_OFF);
  vq_main<<<NV / BM, 256, 0, stream>>>(X, E, eSq, out);
}

// Round 10
// 361.343 us; speedup vs baseline: 2.5233x; 2.5233x over previous
//
#include <hip/hip_runtime.h>

typedef float f4 __attribute__((ext_vector_type(4)));
typedef __attribute__((ext_vector_type(4))) float f32x4;
typedef __attribute__((ext_vector_type(8))) short bf16x8;

#define NV 65536       // total vectors (16*4096)
#define D 64           // embedding dim
#define K 1024         // codebook size
#define BM 64          // vectors per block (4 waves x 16)
#define TILE 128       // codes per LDS tile (8 tiles)
#define NTILES 8
#define CAP 14
#define MARGINF 4.02e-3f  // r8-proven 4e-3 + key-packing slop
#define LOSS_OFF 4194304
#define IDX_OFF  4194305

__device__ __forceinline__ unsigned f2bf(float f) {  // RNE fp32->bf16
  unsigned u = __builtin_bit_cast(unsigned, f);
  return (u + 0x7fffu + ((u >> 16) & 1u)) >> 16;
}

// monotone float<->int key map (self-inverse on the int pattern)
__device__ __forceinline__ int f2ord(float f) {
  int iu = __builtin_bit_cast(int, f);
  return iu ^ ((iu >> 31) & 0x7fffffff);
}
__device__ __forceinline__ float ord2f(int k) {
  return __builtin_bit_cast(float, k ^ ((k >> 31) & 0x7fffffff));
}

// Per-code squared norms, replicating numpy fp32 pairwise-8 summation exactly.
__global__ void vq_prep(const float* __restrict__ E, float* __restrict__ eSq,
                        float* __restrict__ loss) {
  int k = blockIdx.x * 256 + threadIdx.x;
  if (k == 0) *loss = 0.0f;
  if (k < K) {
    const float* row = E + (size_t)k * D;
    float r[8];
#pragma unroll
    for (int j = 0; j < 8; ++j) r[j] = __fmul_rn(row[j], row[j]);
#pragma unroll
    for (int i = 8; i < D; i += 8)
#pragma unroll
      for (int j = 0; j < 8; ++j)
        r[j] = __fadd_rn(r[j], __fmul_rn(row[i + j], row[i + j]));
    eSq[k] = __fadd_rn(
        __fadd_rn(__fadd_rn(r[0], r[1]), __fadd_rn(r[2], r[3])),
        __fadd_rn(__fadd_rn(r[4], r[5]), __fadd_rn(r[6], r[7])));
  }
}

// Stage one 128-code tile of E as bf16 into XOR-swizzled LDS (2 thr/row).
__device__ __forceinline__ void stage_tile(const float* __restrict__ E,
                                           unsigned short* dstbase, int tile,
                                           int t) {
  const int rc = t >> 1, h = t & 1;
  const float* src = E + ((size_t)(tile * TILE + rc)) * D + h * 32;
  char* dst = reinterpret_cast<char*>(dstbase) + rc * 128;
  const int sw = (rc & 7) << 4;
#pragma unroll
  for (int s = 0; s < 4; ++s) {
    f4 a = *reinterpret_cast<const f4*>(src + s * 8);
    f4 b = *reinterpret_cast<const f4*>(src + s * 8 + 4);
    uint4 pk;
    pk.x = f2bf(a[0]) | (f2bf(a[1]) << 16);
    pk.y = f2bf(a[2]) | (f2bf(a[3]) << 16);
    pk.z = f2bf(b[0]) | (f2bf(b[1]) << 16);
    pk.w = f2bf(b[2]) | (f2bf(b[3]) << 16);
    *reinterpret_cast<uint4*>(dst + ((h * 64 + s * 16) ^ sw)) = pk;
  }
}

__device__ __forceinline__ bf16x8 ld_a(const float* p) {
  f4 a = *reinterpret_cast<const f4*>(p);
  f4 b = *reinterpret_cast<const f4*>(p + 4);
  bf16x8 r;
  r[0] = (short)f2bf(a[0]); r[1] = (short)f2bf(a[1]);
  r[2] = (short)f2bf(a[2]); r[3] = (short)f2bf(a[3]);
  r[4] = (short)f2bf(b[0]); r[5] = (short)f2bf(b[1]);
  r[6] = (short)f2bf(b[2]); r[7] = (short)f2bf(b[3]);
  return r;
}

// Single MFMA pass.  Per (lane, vector-row): exact top-4-min stash of packed
// keys (u | code).  After the scan: A* = cross-lane min, collect stash
// entries <= A*+M; provably-sound flag (s3 <= thr) -> exact full rescan.
__global__ __launch_bounds__(256, 4) void vq_main(
    const float* __restrict__ X, const float* __restrict__ E,
    const float* __restrict__ eSq, float* __restrict__ out) {
  __shared__ unsigned short EbfL[2][TILE * 64];  // 2 x 16 KB, swizzled
  __shared__ float eSqL[K];                      // 4 KB
  __shared__ unsigned cntL[BM];
  __shared__ int flagL[BM];
  __shared__ unsigned short candL[BM * CAP];
  __shared__ int sidxL[BM];

  const int t = threadIdx.x;
  const int lane = t & 63;
  const int w = t >> 6;
  const int l15 = lane & 15, l4 = lane >> 4;
  const int bv0 = blockIdx.x * BM;

  // A-fragments from global X (one 16-row tile per wave), bf16 in registers.
  const float* xv = X + (size_t)(bv0 + w * 16 + l15) * D;
  bf16x8 a0 = ld_a(xv + l4 * 8);
  bf16x8 a1 = ld_a(xv + 32 + l4 * 8);

#pragma unroll
  for (int i = 0; i < 4; ++i) eSqL[t + 256 * i] = eSq[t + 256 * i];
  if (t < BM) { cntL[t] = 0; flagL[t] = 0; }
  stage_tile(E, EbfL[0], 0, t);
  __syncthreads();

  int s[4][4];
#pragma unroll
  for (int r = 0; r < 4; ++r)
#pragma unroll
    for (int j = 0; j < 4; ++j) s[r][j] = 0x7fffffff;

#pragma unroll 1
  for (int p = 0; p < NTILES; ++p) {
    if (p < NTILES - 1) stage_tile(E, EbfL[(p + 1) & 1], p + 1, t);
    const char* eB = reinterpret_cast<const char*>(EbfL[p & 1]);
#pragma unroll 2
    for (int ct = 0; ct < 8; ++ct) {
      const int lr = ct * 16 + l15;
      const int rsw = (lr & 7) << 4;
      bf16x8 b0 = *reinterpret_cast<const bf16x8*>(eB + lr * 128 + ((l4 * 16) ^ rsw));
      bf16x8 b1 = *reinterpret_cast<const bf16x8*>(eB + lr * 128 + ((64 + l4 * 16) ^ rsw));
      f32x4 acc = {0.f, 0.f, 0.f, 0.f};
      acc = __builtin_amdgcn_mfma_f32_16x16x32_bf16(a0, b0, acc, 0, 0, 0);
      acc = __builtin_amdgcn_mfma_f32_16x16x32_bf16(a1, b1, acc, 0, 0, 0);
      const int gc = p * TILE + lr;
      const float ee = eSqL[gc];
#pragma unroll
      for (int r = 0; r < 4; ++r) {
        const float u = __fmaf_rn(-2.0f, acc[r], ee);
        int kk = (f2ord(u) & 0xfffffc00) | gc;
        int tt = min(s[r][3], kk);                       // drop max of 5
        s[r][3] = max(s[r][2], tt); tt = min(s[r][2], tt);
        s[r][2] = max(s[r][1], tt); tt = min(s[r][1], tt);
        s[r][1] = max(s[r][0], tt); s[r][0] = min(s[r][0], tt);
      }
    }
    __syncthreads();
  }

  // ---- merge: A* per vector, collect candidates, soundness flag ----
#pragma unroll
  for (int r = 0; r < 4; ++r) {
    int kmin = s[r][0];
#pragma unroll
    for (int off = 1; off < 16; off <<= 1)
      kmin = min(kmin, __shfl_xor(kmin, off, 64));
    const float uA = ord2f(kmin & 0xfffffc00);
    const int thrkey = f2ord(uA + MARGINF) | 1023;
    const int v = w * 16 + l4 * 4 + r;
#pragma unroll
    for (int j = 0; j < 4; ++j) {
      if (s[r][j] <= thrkey) {
        unsigned pos = atomicAdd(&cntL[v], 1u);
        if (pos < CAP) candL[v * CAP + pos] = (unsigned short)(s[r][j] & 1023);
      }
    }
    if (s[r][3] <= thrkey) flagL[v] = 1;  // lane may have evicted a candidate
  }
  __syncthreads();

  // ====== exact fp32 rescore (bit-identical chain to passing rounds) ======
  {
    const int v = t >> 2, par = t & 3;
    const int gv = bv0 + v;
    const float* xr = X + (size_t)gv * D;
    float rr[8];
#pragma unroll
    for (int j = 0; j < 8; ++j) rr[j] = __fmul_rn(xr[j], xr[j]);
#pragma unroll
    for (int i = 8; i < 64; i += 8)
#pragma unroll
      for (int j = 0; j < 8; ++j)
        rr[j] = __fadd_rn(rr[j], __fmul_rn(xr[i + j], xr[i + j]));
    const float xx = __fadd_rn(
        __fadd_rn(__fadd_rn(rr[0], rr[1]), __fadd_rn(rr[2], rr[3])),
        __fadd_rn(__fadd_rn(rr[4], rr[5]), __fadd_rn(rr[6], rr[7])));

    float best = 3.4e38f;
    int bi = 0x7fffffff;
    const unsigned n = cntL[v];
    if (flagL[v] == 0 && n <= CAP) {
      for (unsigned i = par; i < n; i += 4) {
        const int c = candL[v * CAP + i];
        const float* er = E + (size_t)c * D;
        float m = 0.f;
#pragma unroll
        for (int j = 0; j < 64; ++j) m = fmaf(er[j], xr[j], m);
        const float dd = __fsub_rn(__fadd_rn(xx, eSqL[c]), 2.0f * m);
        if (dd < best || (dd == best && c < bi)) { best = dd; bi = c; }
      }
    } else {  // sound fallback: exact full scan (astronomically rare)
      for (int c = par; c < K; c += 4) {
        const float* er = E + (size_t)c * D;
        float m = 0.f;
#pragma unroll
        for (int j = 0; j < 64; ++j) m = fmaf(er[j], xr[j], m);
        const float dd = __fsub_rn(__fadd_rn(xx, eSqL[c]), 2.0f * m);
        if (dd < best || (dd == best && c < bi)) { best = dd; bi = c; }
      }
    }
#pragma unroll
    for (int off = 1; off < 4; off <<= 1) {
      const float ov = __shfl_xor(best, off, 64);
      const int oi = __shfl_xor(bi, off, 64);
      if (ov < best || (ov == best && oi < bi)) { best = ov; bi = oi; }
    }
    if (par == 0) sidxL[v] = bi;
  }
  __syncthreads();

  // ============== epilogue: quantized out, indices, loss ==================
  {
    const int v = t >> 2, h = t & 3;
    const int gv = bv0 + v;
    const int code = sidxL[v];
    const f4* er = reinterpret_cast<const f4*>(E + (size_t)code * D + h * 16);
    const f4* xr = reinterpret_cast<const f4*>(X + (size_t)gv * D + h * 16);
    f4* op = reinterpret_cast<f4*>(out + (size_t)gv * D + h * 16);
    float lsum = 0.f;
#pragma unroll
    for (int i = 0; i < 4; ++i) {
      f4 e4 = er[i], x4 = xr[i];
      float d0 = e4[0] - x4[0], d1 = e4[1] - x4[1];
      float d2 = e4[2] - x4[2], d3 = e4[3] - x4[3];
      lsum += d0 * d0 + d1 * d1 + d2 * d2 + d3 * d3;
      op[i] = e4;
    }
    if (t < BM) out[IDX_OFF + bv0 + t] = (float)sidxL[t];
#pragma unroll
    for (int off = 1; off < 64; off <<= 1) lsum += __shfl_xor(lsum, off, 64);
    if (lane == 0)
      atomicAdd(out + LOSS_OFF, lsum * (1.25f / (float)(NV * (size_t)D)));
  }
}

extern "C" void kernel_launch(void* const* d_in, const int* in_sizes, int n_in,
                              void* d_out, int out_size, void* d_ws, size_t ws_size,
                              hipStream_t stream) {
  const float* X = (const float*)d_in[0];
  const float* E = (const float*)d_in[1];
  float* out = (float*)d_out;
  float* eSq = (float*)d_ws;  // 4 KB scratch
  vq_prep<<<4, 256, 0, stream>>>(E, eSq, out + LOSS_OFF);
  vq_main<<<NV / BM, 256, 0, stream>>>(X, E, eSq, out);
}

// Round 11
// 297.644 us; speedup vs baseline: 3.0633x; 1.2140x over previous
//
#include <hip/hip_runtime.h>

typedef float f4 __attribute__((ext_vector_type(4)));
typedef __attribute__((ext_vector_type(4))) float f32x4;
typedef __attribute__((ext_vector_type(8))) short bf16x8;

#define NV 65536       // total vectors (16*4096)
#define D 64           // embedding dim
#define K 1024         // codebook size
#define BM 64          // vectors per block (4 waves x 16)
#define CAP 16
#define MARGINF 4.02e-3f  // r8/r10-validated margin + key-packing slop
#define LOSS_OFF 4194304
#define IDX_OFF  4194305

__device__ __forceinline__ unsigned f2bf(float f) {  // RNE fp32->bf16
  unsigned u = __builtin_bit_cast(unsigned, f);
  return (u + 0x7fffu + ((u >> 16) & 1u)) >> 16;
}
__device__ __forceinline__ int f2ord(float f) {      // monotone float->int
  int iu = __builtin_bit_cast(int, f);
  return iu ^ ((iu >> 31) & 0x7fffffff);
}
__device__ __forceinline__ float ord2f(int k) {
  return __builtin_bit_cast(float, k ^ ((k >> 31) & 0x7fffffff));
}

// Fused prep: (1) numpy-exact eSq per code; (2) loss zero; (3) E -> bf16 in
// MFMA B-fragment layout: slot n (=fi*64+lane), fi=ct*2+half: lane gets
// Ebf16[ct*16+(lane&15)][half*32+(lane>>4)*8 ..+8).  32 blocks x 256 thr.
__global__ void vq_prep(const float* __restrict__ E, float* __restrict__ ws,
                        float* __restrict__ loss) {
  const int n = blockIdx.x * 256 + threadIdx.x;   // 0..8191 = output slot
  float* eSq = ws;
  unsigned short* Ebf = reinterpret_cast<unsigned short*>(ws + K);
  if (n == 0) *loss = 0.0f;
  if (n < K) {
    const float* row = E + (size_t)n * D;
    float r[8];
#pragma unroll
    for (int j = 0; j < 8; ++j) r[j] = __fmul_rn(row[j], row[j]);
#pragma unroll
    for (int i = 8; i < D; i += 8)
#pragma unroll
      for (int j = 0; j < 8; ++j)
        r[j] = __fadd_rn(r[j], __fmul_rn(row[i + j], row[i + j]));
    eSq[n] = __fadd_rn(
        __fadd_rn(__fadd_rn(r[0], r[1]), __fadd_rn(r[2], r[3])),
        __fadd_rn(__fadd_rn(r[4], r[5]), __fadd_rn(r[6], r[7])));
  }
  const int fi = n >> 6, lane = n & 63;
  const int ct = fi >> 1, half = fi & 1;
  const int code = ct * 16 + (lane & 15);
  const int d0 = half * 32 + (lane >> 4) * 8;
  const float* src = E + (size_t)code * D + d0;
  f4 a = *reinterpret_cast<const f4*>(src);
  f4 b = *reinterpret_cast<const f4*>(src + 4);
  uint4 pk;
  pk.x = f2bf(a[0]) | (f2bf(a[1]) << 16);
  pk.y = f2bf(a[2]) | (f2bf(a[3]) << 16);
  pk.z = f2bf(b[0]) | (f2bf(b[1]) << 16);
  pk.w = f2bf(b[2]) | (f2bf(b[3]) << 16);
  *reinterpret_cast<uint4*>(Ebf + (size_t)n * 8) = pk;
}

__device__ __forceinline__ bf16x8 ld_a(const float* p) {
  f4 a = *reinterpret_cast<const f4*>(p);
  f4 b = *reinterpret_cast<const f4*>(p + 4);
  bf16x8 r;
  r[0] = (short)f2bf(a[0]); r[1] = (short)f2bf(a[1]);
  r[2] = (short)f2bf(a[2]); r[3] = (short)f2bf(a[3]);
  r[4] = (short)f2bf(b[0]); r[5] = (short)f2bf(b[1]);
  r[6] = (short)f2bf(b[2]); r[7] = (short)f2bf(b[3]);
  return r;
}

// top-4-min insert into sorted named regs (S0<=S1<=S2<=S3), 7 int ops
#define INS(S, kk)                                                      \
  { int tt = min(S##3, kk);                                             \
    S##3 = max(S##2, tt); tt = min(S##2, tt);                           \
    S##2 = max(S##1, tt); tt = min(S##1, tt);                           \
    S##1 = max(S##0, tt); S##0 = min(S##0, tt); }

// Barrier-free single-pass MFMA scan: B-frags via coalesced global loads of
// the pre-swizzled bf16 codebook (L2-resident, no LDS staging, no barriers);
// per-(lane,row) exact top-4 stash of packed (u|code) keys in NAMED regs;
// A*+margin collection; provably-sound overflow flag -> exact full rescan.
__global__ __launch_bounds__(256, 4) void vq_main(
    const float* __restrict__ X, const float* __restrict__ E,
    const float* __restrict__ ws, float* __restrict__ out) {
  __shared__ float eSqL[K];                  // 4 KB
  __shared__ unsigned cntL[BM];
  __shared__ int flagL[BM];
  __shared__ unsigned short candL[BM * CAP]; // 2 KB
  __shared__ int sidxL[BM];

  const float* eSq = ws;
  const unsigned short* Ebf = reinterpret_cast<const unsigned short*>(ws + K);

  const int t = threadIdx.x;
  const int lane = t & 63;
  const int w = t >> 6;
  const int l15 = lane & 15, l4 = lane >> 4;
  const int bv0 = blockIdx.x * BM;

  // A-fragments from global X (L2-hot), bf16 in registers.
  const float* xv = X + (size_t)(bv0 + w * 16 + l15) * D;
  bf16x8 a0 = ld_a(xv + l4 * 8);
  bf16x8 a1 = ld_a(xv + 32 + l4 * 8);

#pragma unroll
  for (int i = 0; i < 4; ++i) eSqL[t + 256 * i] = eSq[t + 256 * i];
  if (t < BM) { cntL[t] = 0; flagL[t] = 0; }
  __syncthreads();   // the ONLY pre-scan barrier

  int s00 = 0x7fffffff, s01 = 0x7fffffff, s02 = 0x7fffffff, s03 = 0x7fffffff;
  int s10 = 0x7fffffff, s11 = 0x7fffffff, s12 = 0x7fffffff, s13 = 0x7fffffff;
  int s20 = 0x7fffffff, s21 = 0x7fffffff, s22 = 0x7fffffff, s23 = 0x7fffffff;
  int s30 = 0x7fffffff, s31 = 0x7fffffff, s32 = 0x7fffffff, s33 = 0x7fffffff;

  const unsigned short* ebase = Ebf + (size_t)lane * 8;
#pragma unroll 4
  for (int ct = 0; ct < 64; ++ct) {
    bf16x8 b0 = *reinterpret_cast<const bf16x8*>(ebase + ct * 1024);
    bf16x8 b1 = *reinterpret_cast<const bf16x8*>(ebase + ct * 1024 + 512);
    f32x4 acc = {0.f, 0.f, 0.f, 0.f};
    acc = __builtin_amdgcn_mfma_f32_16x16x32_bf16(a0, b0, acc, 0, 0, 0);
    acc = __builtin_amdgcn_mfma_f32_16x16x32_bf16(a1, b1, acc, 0, 0, 0);
    const int gc = ct * 16 + l15;           // code of this lane's column
    const float ee = eSqL[gc];
    { const int kk = (f2ord(__fmaf_rn(-2.0f, acc[0], ee)) & 0xfffffc00) | gc;
      INS(s0, kk) }
    { const int kk = (f2ord(__fmaf_rn(-2.0f, acc[1], ee)) & 0xfffffc00) | gc;
      INS(s1, kk) }
    { const int kk = (f2ord(__fmaf_rn(-2.0f, acc[2], ee)) & 0xfffffc00) | gc;
      INS(s2, kk) }
    { const int kk = (f2ord(__fmaf_rn(-2.0f, acc[3], ee)) & 0xfffffc00) | gc;
      INS(s3, kk) }
  }

  // ---- merge: A* per vector row, collect candidates, soundness flag ----
#define MERGE(S, r)                                                     \
  { int kmin = S##0;                                                    \
    kmin = min(kmin, __shfl_xor(kmin, 1, 64));                          \
    kmin = min(kmin, __shfl_xor(kmin, 2, 64));                          \
    kmin = min(kmin, __shfl_xor(kmin, 4, 64));                          \
    kmin = min(kmin, __shfl_xor(kmin, 8, 64));                          \
    const float uA = ord2f(kmin & 0xfffffc00);                          \
    const int thrkey = f2ord(uA + MARGINF) | 1023;                      \
    const int v = w * 16 + l4 * 4 + r;                                  \
    if (S##0 <= thrkey) {                                               \
      unsigned pos = atomicAdd(&cntL[v], 1u);                           \
      if (pos < CAP) candL[v * CAP + pos] = (unsigned short)(S##0 & 1023); } \
    if (S##1 <= thrkey) {                                               \
      unsigned pos = atomicAdd(&cntL[v], 1u);                           \
      if (pos < CAP) candL[v * CAP + pos] = (unsigned short)(S##1 & 1023); } \
    if (S##2 <= thrkey) {                                               \
      unsigned pos = atomicAdd(&cntL[v], 1u);                           \
      if (pos < CAP) candL[v * CAP + pos] = (unsigned short)(S##2 & 1023); } \
    if (S##3 <= thrkey) flagL[v] = 1; }
  MERGE(s0, 0) MERGE(s1, 1) MERGE(s2, 2) MERGE(s3, 3)
#undef MERGE
  __syncthreads();

  // ====== exact fp32 rescore (bit-identical chain to passing rounds) ======
  {
    const int v = t >> 2, par = t & 3;
    const int gv = bv0 + v;
    const float* xr = X + (size_t)gv * D;
    float rr[8];
#pragma unroll
    for (int j = 0; j < 8; ++j) rr[j] = __fmul_rn(xr[j], xr[j]);
#pragma unroll
    for (int i = 8; i < 64; i += 8)
#pragma unroll
      for (int j = 0; j < 8; ++j)
        rr[j] = __fadd_rn(rr[j], __fmul_rn(xr[i + j], xr[i + j]));
    const float xx = __fadd_rn(
        __fadd_rn(__fadd_rn(rr[0], rr[1]), __fadd_rn(rr[2], rr[3])),
        __fadd_rn(__fadd_rn(rr[4], rr[5]), __fadd_rn(rr[6], rr[7])));

    float best = 3.4e38f;
    int bi = 0x7fffffff;
    const unsigned n = cntL[v];
    if (flagL[v] == 0 && n <= CAP) {
      for (unsigned i = par; i < n; i += 4) {
        const int c = candL[v * CAP + i];
        const float* er = E + (size_t)c * D;
        float m = 0.f;
#pragma unroll
        for (int j = 0; j < 64; ++j) m = fmaf(er[j], xr[j], m);
        const float dd = __fsub_rn(__fadd_rn(xx, eSqL[c]), 2.0f * m);
        if (dd < best || (dd == best && c < bi)) { best = dd; bi = c; }
      }
    } else {  // sound fallback: exact full scan (astronomically rare)
      for (int c = par; c < K; c += 4) {
        const float* er = E + (size_t)c * D;
        float m = 0.f;
#pragma unroll
        for (int j = 0; j < 64; ++j) m = fmaf(er[j], xr[j], m);
        const float dd = __fsub_rn(__fadd_rn(xx, eSqL[c]), 2.0f * m);
        if (dd < best || (dd == best && c < bi)) { best = dd; bi = c; }
      }
    }
#pragma unroll
    for (int off = 1; off < 4; off <<= 1) {
      const float ov = __shfl_xor(best, off, 64);
      const int oi = __shfl_xor(bi, off, 64);
      if (ov < best || (ov == best && oi < bi)) { best = ov; bi = oi; }
    }
    if (par == 0) sidxL[v] = bi;
  }
  __syncthreads();

  // ============== epilogue: quantized out, indices, loss ==================
  {
    const int v = t >> 2, h = t & 3;
    const int gv = bv0 + v;
    const int code = sidxL[v];
    const f4* er = reinterpret_cast<const f4*>(E + (size_t)code * D + h * 16);
    const f4* xr = reinterpret_cast<const f4*>(X + (size_t)gv * D + h * 16);
    f4* op = reinterpret_cast<f4*>(out + (size_t)gv * D + h * 16);
    float lsum = 0.f;
#pragma unroll
    for (int i = 0; i < 4; ++i) {
      f4 e4 = er[i], x4 = xr[i];
      float d0 = e4[0] - x4[0], d1 = e4[1] - x4[1];
      float d2 = e4[2] - x4[2], d3 = e4[3] - x4[3];
      lsum += d0 * d0 + d1 * d1 + d2 * d2 + d3 * d3;
      op[i] = e4;
    }
    if (t < BM) out[IDX_OFF + bv0 + t] = (float)sidxL[t];
#pragma unroll
    for (int off = 1; off < 64; off <<= 1) lsum += __shfl_xor(lsum, off, 64);
    if (lane == 0)
      atomicAdd(out + LOSS_OFF, lsum * (1.25f / (float)(NV * (size_t)D)));
  }
}

extern "C" void kernel_launch(void* const* d_in, const int* in_sizes, int n_in,
                              void* d_out, int out_size, void* d_ws, size_t ws_size,
                              hipStream_t stream) {
  const float* X = (const float*)d_in[0];
  const float* E = (const float*)d_in[1];
  float* out = (float*)d_out;
  float* ws = (float*)d_ws;  // [0..1024): eSq fp32; then 128 KB bf16 B-frags
  vq_prep<<<32, 256, 0, stream>>>(E, ws, out + LOSS_OFF);
  vq_main<<<NV / BM, 256, 0, stream>>>(X, E, ws, out);
}

// Round 12
// 111.779 us; speedup vs baseline: 8.1570x; 2.6628x over previous
//
#include <hip/hip_runtime.h>

typedef float f4 __attribute__((ext_vector_type(4)));
typedef __attribute__((ext_vector_type(4))) float f32x4;
typedef __attribute__((ext_vector_type(8))) short bf16x8;

#define NV 65536       // total vectors (16*4096)
#define D 64           // embedding dim
#define K 1024         // codebook size
#define NT 512         // threads per block (8 waves)
#define BM 128         // vectors per block (8 waves x 16)
#define TILE 256       // codes per LDS tile (4 tiles)
#define MARGIN 4.0e-3f // r8-validated sound margin
#define CAP 32
#define LOSS_OFF 4194304
#define IDX_OFF  4194305

__device__ __forceinline__ unsigned f2bf(float f) {  // RNE fp32->bf16
  unsigned u = __builtin_bit_cast(unsigned, f);
  return (u + 0x7fffu + ((u >> 16) & 1u)) >> 16;
}

// Per-code squared norms, replicating numpy fp32 pairwise-8 summation exactly.
__global__ void vq_prep(const float* __restrict__ E, float* __restrict__ eSq,
                        float* __restrict__ loss) {
  int k = blockIdx.x * 256 + threadIdx.x;
  if (k == 0) *loss = 0.0f;
  if (k < K) {
    const float* row = E + (size_t)k * D;
    float r[8];
#pragma unroll
    for (int j = 0; j < 8; ++j) r[j] = __fmul_rn(row[j], row[j]);
#pragma unroll
    for (int i = 8; i < D; i += 8)
#pragma unroll
      for (int j = 0; j < 8; ++j)
        r[j] = __fadd_rn(r[j], __fmul_rn(row[i + j], row[i + j]));
    eSq[k] = __fadd_rn(
        __fadd_rn(__fadd_rn(r[0], r[1]), __fadd_rn(r[2], r[3])),
        __fadd_rn(__fadd_rn(r[4], r[5]), __fadd_rn(r[6], r[7])));
  }
}

// Stage one 256-code tile of E as bf16 into XOR-swizzled LDS (2 thr/row).
__device__ __forceinline__ void stage_tile(const float* __restrict__ E,
                                           unsigned short* dstbase, int tile,
                                           int t) {
  const int rc = t >> 1, h = t & 1;             // 512 thr: 256 rows x 2 halves
  const float* src = E + ((size_t)(tile * TILE + rc)) * D + h * 32;
  char* dst = reinterpret_cast<char*>(dstbase) + rc * 128;
  const int sw = (rc & 7) << 4;
#pragma unroll
  for (int s = 0; s < 4; ++s) {
    f4 a = *reinterpret_cast<const f4*>(src + s * 8);
    f4 b = *reinterpret_cast<const f4*>(src + s * 8 + 4);
    uint4 pk;
    pk.x = f2bf(a[0]) | (f2bf(a[1]) << 16);
    pk.y = f2bf(a[2]) | (f2bf(a[3]) << 16);
    pk.z = f2bf(b[0]) | (f2bf(b[1]) << 16);
    pk.w = f2bf(b[2]) | (f2bf(b[3]) << 16);
    *reinterpret_cast<uint4*>(dst + ((h * 64 + s * 16) ^ sw)) = pk;
  }
}

__device__ __forceinline__ bf16x8 ld_a(const float* p) {
  f4 a = *reinterpret_cast<const f4*>(p);
  f4 b = *reinterpret_cast<const f4*>(p + 4);
  bf16x8 r;
  r[0] = (short)f2bf(a[0]); r[1] = (short)f2bf(a[1]);
  r[2] = (short)f2bf(a[2]); r[3] = (short)f2bf(a[3]);
  r[4] = (short)f2bf(b[0]); r[5] = (short)f2bf(b[1]);
  r[6] = (short)f2bf(b[2]); r[7] = (short)f2bf(b[3]);
  return r;
}

// r8's proven two-pass MFMA filter at 2x occupancy: 8 waves/block, one
// 16-vector row-tile per wave, A-frags from global (no X-LDS stage).
// Pass 1 = exact bf16-score min A*; pass 2 = collect u <= A*+M; exact fp32
// rescore (reference-exact chain) of the candidates.
__global__ __launch_bounds__(NT, 4) void vq_main(
    const float* __restrict__ X, const float* __restrict__ E,
    const float* __restrict__ eSq, float* __restrict__ out) {
  __shared__ unsigned short EbfL[TILE * 64];   // 32 KB, swizzled
  __shared__ float eSqL[K];                    // 4 KB
  __shared__ unsigned cntL[BM];
  __shared__ unsigned short candL[BM * CAP];   // 8 KB
  __shared__ int sidxL[BM];

  const int t = threadIdx.x;
  const int lane = t & 63;
  const int w = t >> 6;                        // 8 waves
  const int l15 = lane & 15, l4 = lane >> 4;
  const int bv0 = blockIdx.x * BM;

  // A-fragments from global X (L2-hot), bf16 in registers (r9-proven).
  const float* xv = X + (size_t)(bv0 + w * 16 + l15) * D;
  bf16x8 a0 = ld_a(xv + l4 * 8);
  bf16x8 a1 = ld_a(xv + 32 + l4 * 8);

#pragma unroll
  for (int i = 0; i < 2; ++i) eSqL[t + NT * i] = eSq[t + NT * i];
  if (t < BM) cntL[t] = 0;

  float umin[4];
#pragma unroll
  for (int r = 0; r < 4; ++r) umin[r] = 3.4e38f;
  const char* eB = reinterpret_cast<const char*>(EbfL);

  // ================= PASS 1: per-vector min of u = fl(ee - 2*m~) ==========
  for (int tile = 0; tile < 4; ++tile) {
    __syncthreads();                 // prior tile's reads done
    stage_tile(E, EbfL, tile, t);
    __syncthreads();                 // stage visible
#pragma unroll 4
    for (int ct = 0; ct < 16; ++ct) {
      const int lr = ct * 16 + l15;
      const int rsw = (lr & 7) << 4;
      bf16x8 b0 = *reinterpret_cast<const bf16x8*>(eB + lr * 128 + ((l4 * 16) ^ rsw));
      bf16x8 b1 = *reinterpret_cast<const bf16x8*>(eB + lr * 128 + ((64 + l4 * 16) ^ rsw));
      f32x4 acc = {0.f, 0.f, 0.f, 0.f};
      acc = __builtin_amdgcn_mfma_f32_16x16x32_bf16(a0, b0, acc, 0, 0, 0);
      acc = __builtin_amdgcn_mfma_f32_16x16x32_bf16(a1, b1, acc, 0, 0, 0);
      const float ee = eSqL[tile * TILE + lr];
#pragma unroll
      for (int r = 0; r < 4; ++r)
        umin[r] = fminf(umin[r], __fmaf_rn(-2.0f, acc[r], ee));
    }
  }
  // cross-lane (16-group) min -> exact per-vector A*, frozen threshold
  float thr[4];
#pragma unroll
  for (int r = 0; r < 4; ++r) {
#pragma unroll
    for (int off = 1; off < 16; off <<= 1)
      umin[r] = fminf(umin[r], __shfl_xor(umin[r], off, 64));
    thr[r] = umin[r] + MARGIN;
  }

  // ================= PASS 2: collect candidates (u <= A* + M) =============
  for (int tile = 0; tile < 4; ++tile) {
    __syncthreads();
    stage_tile(E, EbfL, tile, t);
    __syncthreads();
#pragma unroll 4
    for (int ct = 0; ct < 16; ++ct) {
      const int lr = ct * 16 + l15;
      const int rsw = (lr & 7) << 4;
      bf16x8 b0 = *reinterpret_cast<const bf16x8*>(eB + lr * 128 + ((l4 * 16) ^ rsw));
      bf16x8 b1 = *reinterpret_cast<const bf16x8*>(eB + lr * 128 + ((64 + l4 * 16) ^ rsw));
      f32x4 acc = {0.f, 0.f, 0.f, 0.f};
      acc = __builtin_amdgcn_mfma_f32_16x16x32_bf16(a0, b0, acc, 0, 0, 0);
      acc = __builtin_amdgcn_mfma_f32_16x16x32_bf16(a1, b1, acc, 0, 0, 0);
      const int gc = tile * TILE + lr;
      const float ee = eSqL[gc];
#pragma unroll
      for (int r = 0; r < 4; ++r) {
        if (__fmaf_rn(-2.0f, acc[r], ee) <= thr[r]) {
          const int v = w * 16 + l4 * 4 + r;
          const unsigned pos = atomicAdd(&cntL[v], 1u);
          if (pos < CAP) candL[v * CAP + pos] = (unsigned short)gc;
        }
      }
    }
  }
  __syncthreads();

  // ====== exact fp32 rescore (bit-identical chain to passing rounds) ======
  {
    const int v = t >> 2, par = t & 3;
    const int gv = bv0 + v;
    const float* xr = X + (size_t)gv * D;
    float rr[8];
#pragma unroll
    for (int j = 0; j < 8; ++j) rr[j] = __fmul_rn(xr[j], xr[j]);
#pragma unroll
    for (int i = 8; i < 64; i += 8)
#pragma unroll
      for (int j = 0; j < 8; ++j)
        rr[j] = __fadd_rn(rr[j], __fmul_rn(xr[i + j], xr[i + j]));
    const float xx = __fadd_rn(
        __fadd_rn(__fadd_rn(rr[0], rr[1]), __fadd_rn(rr[2], rr[3])),
        __fadd_rn(__fadd_rn(rr[4], rr[5]), __fadd_rn(rr[6], rr[7])));

    float best = 3.4e38f;
    int bi = 0x7fffffff;
    const unsigned n = cntL[v];
    if (n <= CAP) {
      for (unsigned i = par; i < n; i += 4) {
        const int c = candL[v * CAP + i];
        const float* er = E + (size_t)c * D;
        float m = 0.f;
#pragma unroll
        for (int j = 0; j < 64; ++j) m = fmaf(er[j], xr[j], m);
        const float dd = __fsub_rn(__fadd_rn(xx, eSqL[c]), 2.0f * m);
        if (dd < best || (dd == best && c < bi)) { best = dd; bi = c; }
      }
    } else {  // overflow fallback: exact full scan (deterministic, correct)
      for (int c = par; c < K; c += 4) {
        const float* er = E + (size_t)c * D;
        float m = 0.f;
#pragma unroll
        for (int j = 0; j < 64; ++j) m = fmaf(er[j], xr[j], m);
        const float dd = __fsub_rn(__fadd_rn(xx, eSqL[c]), 2.0f * m);
        if (dd < best || (dd == best && c < bi)) { best = dd; bi = c; }
      }
    }
#pragma unroll
    for (int off = 1; off < 4; off <<= 1) {
      const float ov = __shfl_xor(best, off, 64);
      const int oi = __shfl_xor(bi, off, 64);
      if (ov < best || (ov == best && oi < bi)) { best = ov; bi = oi; }
    }
    if (par == 0) sidxL[v] = bi;
  }
  __syncthreads();

  // ============== epilogue: quantized out, indices, loss ==================
  {
    const int v = t >> 2, h = t & 3;
    const int gv = bv0 + v;
    const int code = sidxL[v];
    const f4* er = reinterpret_cast<const f4*>(E + (size_t)code * D + h * 16);
    const f4* xr = reinterpret_cast<const f4*>(X + (size_t)gv * D + h * 16);
    f4* op = reinterpret_cast<f4*>(out + (size_t)gv * D + h * 16);
    float lsum = 0.f;
#pragma unroll
    for (int i = 0; i < 4; ++i) {
      f4 e4 = er[i], x4 = xr[i];
      float d0 = e4[0] - x4[0], d1 = e4[1] - x4[1];
      float d2 = e4[2] - x4[2], d3 = e4[3] - x4[3];
      lsum += d0 * d0 + d1 * d1 + d2 * d2 + d3 * d3;
      op[i] = e4;
    }
    if (t < BM) out[IDX_OFF + bv0 + t] = (float)sidxL[t];
#pragma unroll
    for (int off = 1; off < 64; off <<= 1) lsum += __shfl_xor(lsum, off, 64);
    if (lane == 0)
      atomicAdd(out + LOSS_OFF, lsum * (1.25f / (float)(NV * (size_t)D)));
  }
}

extern "C" void kernel_launch(void* const* d_in, const int* in_sizes, int n_in,
                              void* d_out, int out_size, void* d_ws, size_t ws_size,
                              hipStream_t stream) {
  const float* X = (const float*)d_in[0];
  const float* E = (const float*)d_in[1];
  float* out = (float*)d_out;
  float* eSq = (float*)d_ws;  // 4 KB scratch
  vq_prep<<<4, 256, 0, stream>>>(E, eSq, out + LOSS_OFF);
  vq_main<<<NV / BM, NT, 0, stream>>>(X, E, eSq, out);
}